// Round 13
// baseline (72.916 us; speedup 1.0000x reference)
//
#include <hip/hip_runtime.h>

#define BB 8
#define LL 2048
#define DD 512
#define NN 64
#define TT 64
#define CC 32   // LL/TT chunks

typedef __attribute__((ext_vector_type(8))) short bf16x8;
typedef __attribute__((ext_vector_type(4))) float f32x4;

__device__ __forceinline__ float2 cmul(float2 a, float2 b) {
  return make_float2(a.x*b.x - a.y*b.y, a.x*b.y + a.y*b.x);
}
__device__ __forceinline__ unsigned f2b(float f) {   // f32 -> bf16 (RNE)
  union { float f; unsigned u; } v; v.f = f;
  return (v.u + 0x7FFFu + ((v.u >> 16) & 1u)) >> 16;
}
__device__ __forceinline__ float b2f(unsigned h) {
  union { unsigned u; float f; } v; v.u = h << 16; return v.f;
}

// ---------------------------------------------------------------------------
// K0: transpose u[b][l][d] f32 -> ut_hi/ut_lo[b][d][l] bf16 (hi + residual).
// ---------------------------------------------------------------------------
__global__ __launch_bounds__(256) void k0_tr(
    const float* __restrict__ u, ushort* __restrict__ uth,
    ushort* __restrict__ utl) {
  int bid = blockIdx.x;
  int dt8 = bid & 7, lt = (bid >> 3) & 31, b = bid >> 8;
  int l0 = lt * 64, d0 = dt8 * 64;
  int tid = threadIdx.x;
  __shared__ float tl[64][65];         // [l][d]
  #pragma unroll
  for (int it = 0; it < 2; ++it) {
    int row = it * 32 + (tid >> 3), seg = tid & 7;   // row = l
    const float* src = &u[((size_t)(b*LL + l0 + row))*DD + d0 + seg*8];
    float4 v0 = *(const float4*)src;
    float4 v1 = *(const float4*)(src + 4);
    tl[row][seg*8+0]=v0.x; tl[row][seg*8+1]=v0.y;
    tl[row][seg*8+2]=v0.z; tl[row][seg*8+3]=v0.w;
    tl[row][seg*8+4]=v1.x; tl[row][seg*8+5]=v1.y;
    tl[row][seg*8+6]=v1.z; tl[row][seg*8+7]=v1.w;
  }
  __syncthreads();
  #pragma unroll
  for (int it = 0; it < 2; ++it) {
    int row = it * 32 + (tid >> 3), seg = tid & 7;   // row = d
    unsigned h[8], lo[8];
    #pragma unroll
    for (int j = 0; j < 8; ++j) {
      float f = tl[seg*8 + j][row];
      h[j]  = f2b(f);
      lo[j] = f2b(f - b2f(h[j]));
    }
    uint4 ph = make_uint4(h[0]|(h[1]<<16), h[2]|(h[3]<<16),
                          h[4]|(h[5]<<16), h[6]|(h[7]<<16));
    uint4 pl = make_uint4(lo[0]|(lo[1]<<16), lo[2]|(lo[3]<<16),
                          lo[4]|(lo[5]<<16), lo[6]|(lo[7]<<16));
    size_t off = ((size_t)(b*DD + d0 + row))*LL + l0 + seg*8;
    *(uint4*)&uth[off] = ph;
    *(uint4*)&utl[off] = pl;
  }
}

// ---------------------------------------------------------------------------
// K1: per-d setup, 256 threads (wave wv owns a 16-slice of s/r/m).
// Emits pre-swizzled bf16 MFMA B-operand tables W2s/G2s/Th/Tl + P (f32).
// ---------------------------------------------------------------------------
__global__ __launch_bounds__(256) void k1_setup(
    const float* __restrict__ A_re, const float* __restrict__ A_im,
    const float* __restrict__ C_re, const float* __restrict__ C_im,
    const float* __restrict__ log_dt,
    ushort* __restrict__ W2s, ushort* __restrict__ G2s,
    ushort* __restrict__ Th2s, ushort* __restrict__ Tl2s,
    float2* __restrict__ P) {
  int d = blockIdx.x;
  int tid = threadIdx.x;
  int n = tid & 63, wv = tid >> 6;
  int idx = d * NN + n;

  __shared__ ushort Wl[8192], Gl[8192];
  __shared__ __align__(16) char smU[16640];   // Kp f32[64][65] | later Th/Tl
  ushort* Thl = (ushort*)smU;
  ushort* Tll = (ushort*)(smU + 8192);
  float*  Kp  = (float*)smU;
  __shared__ float Kq[64][5];
  __shared__ float Kl[64];

  float dt  = expf(log_dt[d]);
  float dre = dt * A_re[idx], dim = dt * A_im[idx];
  float er  = expf(dre);
  float abr = er * cosf(dim), abi = er * sinf(dim);
  const float eps = 1e-8f;
  float nre = abr - 1.0f + eps, nim = abi;
  float qre = dre + eps,        qim = dim;
  float inv = 1.0f / (qre*qre + qim*qim);
  float bbr = dt * (nre*qre + nim*qim) * inv;
  float bbi = dt * (nim*qre - nre*qim) * inv;
  float2 a  = make_float2(abr, abi);
  float2 bb = make_float2(bbr, bbi);
  float2 cc = make_float2(C_re[idx], C_im[idx]);

  float2 a2  = cmul(a, a),   a4  = cmul(a2, a2);
  float2 a8  = cmul(a4, a4), a16 = cmul(a8, a8);
  float2 a32 = cmul(a16, a16), a48 = cmul(a32, a16);
  float2 pw_wv = make_float2(1.f, 0.f);
  for (int q = 0; q < wv; ++q) pw_wv = cmul(pw_wv, a16);

  if (wv == 0) P[idx] = cmul(a32, a32);

  // W slice: s in [wv*16, wv*16+15], descending; W[s] = bb*a^(63-s)
  {
    float2 sel = (wv == 0) ? a48 : (wv == 1) ? a32
               : (wv == 2) ? a16 : make_float2(1.f, 0.f);
    float2 w = cmul(bb, sel);
    for (int j = 15; j >= 0; --j) {
      int s = wv*16 + j;
      int ks = s >> 5, lk = (s >> 3) & 3, e = s & 7;
      {
        int n2 = 2*n; int nh = n2>>6, tq = (n2>>4)&3, lr = n2&15;
        Wl[(((nh*4+tq)*2+ks)*64 + lk*16+lr)*8 + e] = (ushort)f2b(w.x);
      }
      {
        int n2 = 2*n+1; int nh = n2>>6, tq = (n2>>4)&3, lr = n2&15;
        Wl[(((nh*4+tq)*2+ks)*64 + lk*16+lr)*8 + e] = (ushort)f2b(w.y);
      }
      w = cmul(w, a);
    }
  }
  // G slice: r in [wv*16, wv*16+15]; G[r] = cc*a^(r+1)
  {
    float2 g = cmul(cc, cmul(a, pw_wv));
    for (int j = 0; j < 16; ++j) {
      int r = wv*16 + j;
      int rh = r >> 5, tq = (r >> 4) & 1, lr = r & 15;
      {
        int n2 = 2*n; int ks = n2>>5, lk = (n2>>3)&3, e = n2&7;
        Gl[(((rh*2+tq)*4+ks)*64 + lk*16+lr)*8 + e] = (ushort)f2b(g.x);
      }
      {
        int n2 = 2*n+1; int ks = n2>>5, lk = (n2>>3)&3, e = n2&7;
        Gl[(((rh*2+tq)*4+ks)*64 + lk*16+lr)*8 + e] = (ushort)f2b(-g.y);
      }
      g = cmul(g, a);
    }
  }
  // K slice: Kp[m][n] = Re(cb * a^m), m in [wv*16, wv*16+15]
  {
    float2 cb = cmul(cc, bb);
    float2 t = cmul(cb, pw_wv);
    for (int j = 0; j < 16; ++j) {
      Kp[(wv*16 + j)*65 + n] = t.x;
      t = cmul(t, a);
    }
  }
  __syncthreads();
  {
    int m = tid >> 2, q = tid & 3;
    float s = 0.f;
    #pragma unroll
    for (int j = 0; j < 16; ++j) s += Kp[m*65 + q*16 + j];
    Kq[m][q] = s;
  }
  __syncthreads();
  if (tid < 64) Kl[tid] = Kq[tid][0] + Kq[tid][1] + Kq[tid][2] + Kq[tid][3];
  __syncthreads();                     // Kl ready; Kp dead -> Th/Tl reuse smU

  // Toeplitz frags (hi+lo): wave wv = (t*2+ks); 16 elems/thread
  {
    int tq = wv >> 1, ks = wv & 1;
    #pragma unroll
    for (int rh = 0; rh < 2; ++rh) {
      int r = rh*32 + tq*16 + (n & 15);
      #pragma unroll
      for (int e = 0; e < 8; ++e) {
        int s = ks*32 + (n >> 4)*8 + e;
        float val = (s <= r) ? Kl[r - s] : 0.f;
        unsigned hv = f2b(val);
        int o = rh*2048 + (wv*64 + n)*8 + e;
        Thl[o] = (ushort)hv;
        Tll[o] = (ushort)f2b(val - b2f(hv));
      }
    }
  }
  __syncthreads();
  {
    uint4* Wg  = (uint4*)(W2s  + (size_t)d * 8192);
    uint4* Gg  = (uint4*)(G2s  + (size_t)d * 8192);
    uint4* Thg = (uint4*)(Th2s + (size_t)d * 4096);
    uint4* Tlg = (uint4*)(Tl2s + (size_t)d * 4096);
    #pragma unroll
    for (int i = tid; i < 1024; i += 256) {
      Wg[i] = ((const uint4*)Wl)[i];
      Gg[i] = ((const uint4*)Gl)[i];
    }
    #pragma unroll
    for (int i = tid; i < 512; i += 256) {
      Thg[i] = ((const uint4*)Thl)[i];
      Tlg[i] = ((const uint4*)Tll)[i];
    }
  }
}

// ---------------------------------------------------------------------------
// K2 MFMA: Z-GEMM (u hi+lo) + split Toeplitz conv + Kogge-Stone scan
// (round-10-proven, double-barrier) + split cross-GEMM (S hi+lo).
// FULLY DISJOINT LDS - no buffer aliasing anywhere (49.8KB, 3 blocks/CU).
// Table-fragment loads hoisted: W/Th/Tl before the stage barrier, G after
// phase T (in flight across the scan).
// ---------------------------------------------------------------------------
__global__ __launch_bounds__(256, 3) void k2_mfma(
    const ushort* __restrict__ uth, const ushort* __restrict__ utl,
    const ushort* __restrict__ W2s, const ushort* __restrict__ G2s,
    const ushort* __restrict__ Th2s, const ushort* __restrict__ Tl2s,
    const float2* __restrict__ P, float* __restrict__ yt) {
  int bid = blockIdx.x;
  int x = bid & 7;                     // XCD
  int d = x * 64 + ((bid >> 3) & 63);  // d-contiguous per XCD
  int b = bid >> 9;
  int tid = threadIdx.x;
  int l = tid & 63, wv = tid >> 6;
  int lr = l & 15, lk = l >> 4;
  int m0 = (wv & 1) * 16;              // c-half
  int half = wv >> 1;                  // n-half (B) / r-half (T,D)

  // Disjoint LDS map (total 50960 B):
  //  [0,4096)        u_hi  [32][128B]
  //  [4096,8192)     u_lo
  //  [8192,25360)    Sf    [33][130] f32 (17160 + 8 pad)
  //  [25360,33808)   Zs    [33][256B] S_excl hi
  //  [33808,42256)   Zl    [33][256B] S_excl lo
  //  [42256,50960)   ylds  [32][68] f32
  __shared__ __align__(16) char smem[50960];
  char*  u_hi = smem;
  char*  u_lo = smem + 4096;
  float* Sf   = (float*)(smem + 8192);
  char*  Zs   = smem + 25360;
  char*  Zl   = smem + 33808;
  float* ylds = (float*)(smem + 42256);

  // --- hoisted loads: W/Th/Tl fragments + P (in flight during stage)
  bf16x8 wf[8], tfh[4], tfl[4];
  {
    const ushort* Wd  = W2s  + (size_t)d * 8192 + (size_t)half * 4096;
    const ushort* Tdh = Th2s + (size_t)d * 4096 + (size_t)half * 2048;
    const ushort* Tdl = Tl2s + (size_t)d * 4096 + (size_t)half * 2048;
    #pragma unroll
    for (int t = 0; t < 4; ++t)
      #pragma unroll
      for (int ks = 0; ks < 2; ++ks)
        wf[t*2+ks] = *(const bf16x8*)(Wd + ((t*2 + ks)*64 + l)*8);
    #pragma unroll
    for (int t = 0; t < 2; ++t)
      #pragma unroll
      for (int ks = 0; ks < 2; ++ks) {
        tfh[t*2+ks] = *(const bf16x8*)(Tdh + ((t*2 + ks)*64 + l)*8);
        tfl[t*2+ks] = *(const bf16x8*)(Tdl + ((t*2 + ks)*64 + l)*8);
      }
  }
  float2 p0 = P[(size_t)d * NN + l];   // a^64 (lane l = state index n)

  // --- stage u_hi/u_lo (coalesced 16B loads), rows 0..31; zero Sf row 0
  {
    size_t off = ((size_t)(b * DD + d)) * LL + tid * 8;
    uint4 vh = *(const uint4*)&uth[off];
    uint4 vl = *(const uint4*)&utl[off];
    int row = tid >> 3;
    int bo = row*128 + (((tid & 7) * 16) ^ ((row & 7) << 4));
    *(uint4*)(u_hi + bo) = vh;
    *(uint4*)(u_lo + bo) = vl;
  }
  for (int i = tid; i < 130; i += 256) Sf[i] = 0.f;   // Sf row 0 = zeros
  __syncthreads();

  // --- B: Z-GEMM, u hi+lo -> Sf rows c+1 (de-interleaved re/im cols)
  {
    f32x4 acc[4] = {{0,0,0,0},{0,0,0,0},{0,0,0,0},{0,0,0,0}};
    #pragma unroll
    for (int ks = 0; ks < 2; ++ks) {
      int arow = m0 + lr;
      int aoff = (ks*64 + lk*16) ^ ((arow & 7) << 4);
      bf16x8 ah = *(const bf16x8*)(u_hi + arow*128 + aoff);
      bf16x8 al = *(const bf16x8*)(u_lo + arow*128 + aoff);
      #pragma unroll
      for (int t = 0; t < 4; ++t) {
        acc[t] = __builtin_amdgcn_mfma_f32_16x16x32_bf16(ah, wf[t*2+ks], acc[t], 0,0,0);
        acc[t] = __builtin_amdgcn_mfma_f32_16x16x32_bf16(al, wf[t*2+ks], acc[t], 0,0,0);
      }
    }
    #pragma unroll
    for (int t = 0; t < 4; ++t)
      #pragma unroll
      for (int j = 0; j < 4; ++j) {
        int c  = m0 + lk*4 + j;
        int n2 = half*64 + t*16 + lr;
        int col = (n2 >> 1) + (n2 & 1) * 64;
        Sf[(c + 1) * 130 + col] = acc[t][j];
      }
  }

  // --- T: split-precision local conv GEMM into acc2
  f32x4 acc2[2] = {{0,0,0,0},{0,0,0,0}};
  {
    #pragma unroll
    for (int ks = 0; ks < 2; ++ks) {
      int arow = m0 + lr;
      int aoff = (ks*64 + lk*16) ^ ((arow & 7) << 4);
      bf16x8 ah = *(const bf16x8*)(u_hi + arow*128 + aoff);
      bf16x8 al = *(const bf16x8*)(u_lo + arow*128 + aoff);
      #pragma unroll
      for (int t = 0; t < 2; ++t) {
        acc2[t] = __builtin_amdgcn_mfma_f32_16x16x32_bf16(ah, tfh[t*2+ks], acc2[t], 0,0,0);
        acc2[t] = __builtin_amdgcn_mfma_f32_16x16x32_bf16(al, tfh[t*2+ks], acc2[t], 0,0,0);
        acc2[t] = __builtin_amdgcn_mfma_f32_16x16x32_bf16(ah, tfl[t*2+ks], acc2[t], 0,0,0);
      }
    }
  }

  // --- hoist G fragments (in flight across the whole scan phase)
  bf16x8 gf[8];
  {
    const ushort* Gd = G2s + (size_t)d * 8192 + (size_t)half * 4096;
    #pragma unroll
    for (int t = 0; t < 2; ++t)
      #pragma unroll
      for (int ks = 0; ks < 4; ++ks)
        gf[t*4+ks] = *(const bf16x8*)(Gd + ((t*4 + ks)*64 + l)*8);
  }
  __syncthreads();                     // all Sf writes visible

  // --- Kogge-Stone scan rows 1..32 (round-10 proven): Sf[r] += p^(2^k)*Sf[r-2^k]
  {
    int n = tid & 63;
    int rb = 1 + (tid >> 6);
    float2 p = p0;
    float vre[8], vim[8];
    #pragma unroll
    for (int q = 0; q < 8; ++q) {
      int r = rb + 4*q;
      vre[q] = Sf[r*130 + n];
      vim[q] = Sf[r*130 + 64 + n];
    }
    #pragma unroll
    for (int k = 0; k < 5; ++k) {
      int s = 1 << k;
      float pre[8], pim[8];
      #pragma unroll
      for (int q = 0; q < 8; ++q) {
        int pr = rb + 4*q - s; if (pr < 0) pr = 0;
        pre[q] = Sf[pr*130 + n];
        pim[q] = Sf[pr*130 + 64 + n];
      }
      __syncthreads();                 // reads done
      #pragma unroll
      for (int q = 0; q < 8; ++q) {
        vre[q] = fmaf(p.x, pre[q], fmaf(-p.y, pim[q], vre[q]));
        vim[q] = fmaf(p.x, pim[q], fmaf( p.y, pre[q], vim[q]));
        Sf[(rb + 4*q)*130 + n]      = vre[q];
        Sf[(rb + 4*q)*130 + 64 + n] = vim[q];
      }
      float npx = p.x*p.x - p.y*p.y;
      p.y = 2.f * p.x * p.y; p.x = npx;
      __syncthreads();                 // writes visible
    }
    // emit S_excl rows 1..32 as bf16 hi+lo (swizzled); zero rows 0
    #pragma unroll
    for (int q = 0; q < 8; ++q) {
      int r = rb + 4*q;
      unsigned hx = f2b(vre[q]), hy = f2b(vim[q]);
      unsigned lx = f2b(vre[q] - b2f(hx)), ly = f2b(vim[q] - b2f(hy));
      int off = r*256 + ((4*n) ^ ((r & 7) << 4));
      *(unsigned*)(Zs + off) = hx | (hy << 16);
      *(unsigned*)(Zl + off) = lx | (ly << 16);
    }
    if (tid < 64) {
      *(unsigned*)(Zs + 4*tid) = 0u;   // row 0 = S_excl[0] = 0
      *(unsigned*)(Zl + 4*tid) = 0u;
    }
  }
  __syncthreads();

  // --- D: split cross GEMM (S hi+lo) accumulating into acc2
  {
    #pragma unroll
    for (int ks = 0; ks < 4; ++ks) {
      int arow = m0 + lr;
      int aoff = (ks*64 + lk*16) ^ ((arow & 7) << 4);
      bf16x8 ah = *(const bf16x8*)(Zs + arow*256 + aoff);
      bf16x8 al = *(const bf16x8*)(Zl + arow*256 + aoff);
      #pragma unroll
      for (int t = 0; t < 2; ++t) {
        acc2[t] = __builtin_amdgcn_mfma_f32_16x16x32_bf16(ah, gf[t*4+ks], acc2[t], 0,0,0);
        acc2[t] = __builtin_amdgcn_mfma_f32_16x16x32_bf16(al, gf[t*4+ks], acc2[t], 0,0,0);
      }
    }
  }
  __syncthreads();                     // all Zs/Zl reads done before reuse-free ylds writes

  // --- out: acc2 -> ylds f32 [c][r] stride 68 -> yt linear 8KB
  #pragma unroll
  for (int t = 0; t < 2; ++t)
    #pragma unroll
    for (int j = 0; j < 4; ++j) {
      int c = m0 + lk*4 + j;
      int r = half*32 + t*16 + lr;
      ylds[c*68 + r] = acc2[t][j];
    }
  __syncthreads();
  {
    int row = tid >> 3, col = (tid & 7) * 8;
    float4 o0 = *(const float4*)&ylds[row*68 + col];
    float4 o1 = *(const float4*)&ylds[row*68 + col + 4];
    float* dst = &yt[((size_t)(b * DD + d)) * LL + tid * 8];
    *(float4*)dst = o0;
    *(float4*)(dst + 4) = o1;
  }
}

// ---------------------------------------------------------------------------
// K4: transpose yt[b][d][l] f32 -> y[b][l][d] f32. Full 64x64 coverage.
// ---------------------------------------------------------------------------
__global__ __launch_bounds__(256) void k4_tr(
    const float* __restrict__ yt, float* __restrict__ y) {
  int bid = blockIdx.x;
  int dt8 = bid & 7, lt = (bid >> 3) & 31, b = bid >> 8;
  int l0 = lt * 64, d0 = dt8 * 64;
  int tid = threadIdx.x;
  __shared__ float tl[64][65];         // [d][l]
  #pragma unroll
  for (int it = 0; it < 2; ++it) {
    int row = it * 32 + (tid >> 3), seg = tid & 7;   // row = d
    const float* src = &yt[((size_t)(b*DD + d0 + row))*LL + l0 + seg*8];
    float4 v0 = *(const float4*)src;
    float4 v1 = *(const float4*)(src + 4);
    tl[row][seg*8+0]=v0.x; tl[row][seg*8+1]=v0.y;
    tl[row][seg*8+2]=v0.z; tl[row][seg*8+3]=v0.w;
    tl[row][seg*8+4]=v1.x; tl[row][seg*8+5]=v1.y;
    tl[row][seg*8+6]=v1.z; tl[row][seg*8+7]=v1.w;
  }
  __syncthreads();
  #pragma unroll
  for (int it = 0; it < 2; ++it) {
    int row = it * 32 + (tid >> 3), seg = tid & 7;   // row = l
    float o[8];
    #pragma unroll
    for (int j = 0; j < 8; ++j) o[j] = tl[seg*8 + j][row];
    float* dst = &y[((size_t)(b*LL + l0 + row))*DD + d0 + seg*8];
    *(float4*)dst = *(float4*)&o[0];
    *(float4*)(dst + 4) = *(float4*)&o[4];
  }
}

extern "C" void kernel_launch(void* const* d_in, const int* in_sizes, int n_in,
                              void* d_out, int out_size, void* d_ws, size_t ws_size,
                              hipStream_t stream) {
  const float* u      = (const float*)d_in[0];
  const float* A_re   = (const float*)d_in[1];
  const float* A_im   = (const float*)d_in[2];
  const float* C_re   = (const float*)d_in[3];
  const float* C_im   = (const float*)d_in[4];
  const float* log_dt = (const float*)d_in[5];
  float* y = (float*)d_out;

  // ws: yt f32 33.5MB | uth 16.8 | utl 16.8 | W2s 8.4 | G2s 8.4 | Th 4.2 | Tl 4.2 | P
  float*  yt  = (float*)d_ws;
  ushort* uth = (ushort*)(yt + (size_t)BB * DD * LL);
  ushort* utl = uth + (size_t)BB * DD * LL;
  ushort* W2s = utl + (size_t)BB * DD * LL;
  ushort* G2s = W2s + (size_t)DD * 8192;
  ushort* Th  = G2s + (size_t)DD * 8192;
  ushort* Tl  = Th  + (size_t)DD * 4096;
  float2* P   = (float2*)(Tl + (size_t)DD * 4096);

  k0_tr   <<<BB * 32 * 8, 256, 0, stream>>>(u, uth, utl);
  k1_setup<<<DD,          256, 0, stream>>>(A_re, A_im, C_re, C_im, log_dt,
                                            W2s, G2s, Th, Tl, P);
  k2_mfma <<<BB * DD,     256, 0, stream>>>(uth, utl, W2s, G2s, Th, Tl, P, yt);
  k4_tr   <<<BB * 32 * 8, 256, 0, stream>>>(yt, y);
}

// Round 14
// 63.340 us; speedup vs baseline: 1.1512x; 1.1512x over previous
//
#include <hip/hip_runtime.h>

#define BB 8
#define LL 2048
#define DD 512
#define NN 64
#define TT 64
#define CC 32   // LL/TT chunks

typedef __attribute__((ext_vector_type(8))) short bf16x8;
typedef __attribute__((ext_vector_type(4))) float f32x4;

__device__ __forceinline__ float2 cmul(float2 a, float2 b) {
  return make_float2(a.x*b.x - a.y*b.y, a.x*b.y + a.y*b.x);
}
__device__ __forceinline__ unsigned f2b(float f) {   // f32 -> bf16 (RNE)
  union { float f; unsigned u; } v; v.f = f;
  return (v.u + 0x7FFFu + ((v.u >> 16) & 1u)) >> 16;
}
__device__ __forceinline__ float b2f(unsigned h) {
  union { unsigned u; float f; } v; v.u = h << 16; return v.f;
}

// ---------------------------------------------------------------------------
// K0: transpose u[b][l][d] f32 -> ut_hi/ut_lo[b][d][l] bf16 (hi + residual).
// ---------------------------------------------------------------------------
__global__ __launch_bounds__(256) void k0_tr(
    const float* __restrict__ u, ushort* __restrict__ uth,
    ushort* __restrict__ utl) {
  int bid = blockIdx.x;
  int dt8 = bid & 7, lt = (bid >> 3) & 31, b = bid >> 8;
  int l0 = lt * 64, d0 = dt8 * 64;
  int tid = threadIdx.x;
  __shared__ float tl[64][65];         // [l][d]
  #pragma unroll
  for (int it = 0; it < 2; ++it) {
    int row = it * 32 + (tid >> 3), seg = tid & 7;   // row = l
    const float* src = &u[((size_t)(b*LL + l0 + row))*DD + d0 + seg*8];
    float4 v0 = *(const float4*)src;
    float4 v1 = *(const float4*)(src + 4);
    tl[row][seg*8+0]=v0.x; tl[row][seg*8+1]=v0.y;
    tl[row][seg*8+2]=v0.z; tl[row][seg*8+3]=v0.w;
    tl[row][seg*8+4]=v1.x; tl[row][seg*8+5]=v1.y;
    tl[row][seg*8+6]=v1.z; tl[row][seg*8+7]=v1.w;
  }
  __syncthreads();
  #pragma unroll
  for (int it = 0; it < 2; ++it) {
    int row = it * 32 + (tid >> 3), seg = tid & 7;   // row = d
    unsigned h[8], lo[8];
    #pragma unroll
    for (int j = 0; j < 8; ++j) {
      float f = tl[seg*8 + j][row];
      h[j]  = f2b(f);
      lo[j] = f2b(f - b2f(h[j]));
    }
    uint4 ph = make_uint4(h[0]|(h[1]<<16), h[2]|(h[3]<<16),
                          h[4]|(h[5]<<16), h[6]|(h[7]<<16));
    uint4 pl = make_uint4(lo[0]|(lo[1]<<16), lo[2]|(lo[3]<<16),
                          lo[4]|(lo[5]<<16), lo[6]|(lo[7]<<16));
    size_t off = ((size_t)(b*DD + d0 + row))*LL + l0 + seg*8;
    *(uint4*)&uth[off] = ph;
    *(uint4*)&utl[off] = pl;
  }
}

// ---------------------------------------------------------------------------
// K1: per-d setup, 256 threads (wave wv owns a 16-slice of s/r/m).
// Emits pre-swizzled bf16 MFMA B-operand tables W2s/G2s/Th/Tl + P (f32).
// ---------------------------------------------------------------------------
__global__ __launch_bounds__(256) void k1_setup(
    const float* __restrict__ A_re, const float* __restrict__ A_im,
    const float* __restrict__ C_re, const float* __restrict__ C_im,
    const float* __restrict__ log_dt,
    ushort* __restrict__ W2s, ushort* __restrict__ G2s,
    ushort* __restrict__ Th2s, ushort* __restrict__ Tl2s,
    float2* __restrict__ P) {
  int d = blockIdx.x;
  int tid = threadIdx.x;
  int n = tid & 63, wv = tid >> 6;
  int idx = d * NN + n;

  __shared__ ushort Wl[8192], Gl[8192];
  __shared__ __align__(16) char smU[16640];   // Kp f32[64][65] | later Th/Tl
  ushort* Thl = (ushort*)smU;
  ushort* Tll = (ushort*)(smU + 8192);
  float*  Kp  = (float*)smU;
  __shared__ float Kq[64][5];
  __shared__ float Kl[64];

  float dt  = expf(log_dt[d]);
  float dre = dt * A_re[idx], dim = dt * A_im[idx];
  float er  = expf(dre);
  float abr = er * cosf(dim), abi = er * sinf(dim);
  const float eps = 1e-8f;
  float nre = abr - 1.0f + eps, nim = abi;
  float qre = dre + eps,        qim = dim;
  float inv = 1.0f / (qre*qre + qim*qim);
  float bbr = dt * (nre*qre + nim*qim) * inv;
  float bbi = dt * (nim*qre - nre*qim) * inv;
  float2 a  = make_float2(abr, abi);
  float2 bb = make_float2(bbr, bbi);
  float2 cc = make_float2(C_re[idx], C_im[idx]);

  float2 a2  = cmul(a, a),   a4  = cmul(a2, a2);
  float2 a8  = cmul(a4, a4), a16 = cmul(a8, a8);
  float2 a32 = cmul(a16, a16), a48 = cmul(a32, a16);
  float2 pw_wv = make_float2(1.f, 0.f);
  for (int q = 0; q < wv; ++q) pw_wv = cmul(pw_wv, a16);

  if (wv == 0) P[idx] = cmul(a32, a32);

  // W slice: s in [wv*16, wv*16+15], descending; W[s] = bb*a^(63-s)
  {
    float2 sel = (wv == 0) ? a48 : (wv == 1) ? a32
               : (wv == 2) ? a16 : make_float2(1.f, 0.f);
    float2 w = cmul(bb, sel);
    for (int j = 15; j >= 0; --j) {
      int s = wv*16 + j;
      int ks = s >> 5, lk = (s >> 3) & 3, e = s & 7;
      {
        int n2 = 2*n; int nh = n2>>6, tq = (n2>>4)&3, lr = n2&15;
        Wl[(((nh*4+tq)*2+ks)*64 + lk*16+lr)*8 + e] = (ushort)f2b(w.x);
      }
      {
        int n2 = 2*n+1; int nh = n2>>6, tq = (n2>>4)&3, lr = n2&15;
        Wl[(((nh*4+tq)*2+ks)*64 + lk*16+lr)*8 + e] = (ushort)f2b(w.y);
      }
      w = cmul(w, a);
    }
  }
  // G slice: r in [wv*16, wv*16+15]; G[r] = cc*a^(r+1)
  {
    float2 g = cmul(cc, cmul(a, pw_wv));
    for (int j = 0; j < 16; ++j) {
      int r = wv*16 + j;
      int rh = r >> 5, tq = (r >> 4) & 1, lr = r & 15;
      {
        int n2 = 2*n; int ks = n2>>5, lk = (n2>>3)&3, e = n2&7;
        Gl[(((rh*2+tq)*4+ks)*64 + lk*16+lr)*8 + e] = (ushort)f2b(g.x);
      }
      {
        int n2 = 2*n+1; int ks = n2>>5, lk = (n2>>3)&3, e = n2&7;
        Gl[(((rh*2+tq)*4+ks)*64 + lk*16+lr)*8 + e] = (ushort)f2b(-g.y);
      }
      g = cmul(g, a);
    }
  }
  // K slice: Kp[m][n] = Re(cb * a^m), m in [wv*16, wv*16+15]
  {
    float2 cb = cmul(cc, bb);
    float2 t = cmul(cb, pw_wv);
    for (int j = 0; j < 16; ++j) {
      Kp[(wv*16 + j)*65 + n] = t.x;
      t = cmul(t, a);
    }
  }
  __syncthreads();
  {
    int m = tid >> 2, q = tid & 3;
    float s = 0.f;
    #pragma unroll
    for (int j = 0; j < 16; ++j) s += Kp[m*65 + q*16 + j];
    Kq[m][q] = s;
  }
  __syncthreads();
  if (tid < 64) Kl[tid] = Kq[tid][0] + Kq[tid][1] + Kq[tid][2] + Kq[tid][3];
  __syncthreads();                     // Kl ready; Kp dead -> Th/Tl reuse smU

  // Toeplitz frags (hi+lo): wave wv = (t*2+ks); 16 elems/thread
  {
    int tq = wv >> 1, ks = wv & 1;
    #pragma unroll
    for (int rh = 0; rh < 2; ++rh) {
      int r = rh*32 + tq*16 + (n & 15);
      #pragma unroll
      for (int e = 0; e < 8; ++e) {
        int s = ks*32 + (n >> 4)*8 + e;
        float val = (s <= r) ? Kl[r - s] : 0.f;
        unsigned hv = f2b(val);
        int o = rh*2048 + (wv*64 + n)*8 + e;
        Thl[o] = (ushort)hv;
        Tll[o] = (ushort)f2b(val - b2f(hv));
      }
    }
  }
  __syncthreads();
  {
    uint4* Wg  = (uint4*)(W2s  + (size_t)d * 8192);
    uint4* Gg  = (uint4*)(G2s  + (size_t)d * 8192);
    uint4* Thg = (uint4*)(Th2s + (size_t)d * 4096);
    uint4* Tlg = (uint4*)(Tl2s + (size_t)d * 4096);
    #pragma unroll
    for (int i = tid; i < 1024; i += 256) {
      Wg[i] = ((const uint4*)Wl)[i];
      Gg[i] = ((const uint4*)Gl)[i];
    }
    #pragma unroll
    for (int i = tid; i < 512; i += 256) {
      Thg[i] = ((const uint4*)Thl)[i];
      Tlg[i] = ((const uint4*)Tll)[i];
    }
  }
}

// ---------------------------------------------------------------------------
// K2 MFMA: Z-GEMM (u_hi) + split Toeplitz conv + register-chain scan +
// cross-GEMM; writes yt[b][d][:] f32 coalesced.
// FULLY DISJOINT LDS (43.8KB, 3 blocks/CU) - no buffer aliasing anywhere.
// Scan: thread (n,wv) owns chunks [8wv,8wv+8): 7 in-register cmuls, one Tb
// write, 1 barrier, <=3-term cross-wave combine with p^8 (wave-uniform).
// 5 barriers total (was 15 with Kogge-Stone).
// ---------------------------------------------------------------------------
__global__ __launch_bounds__(256, 3) void k2_mfma(
    const ushort* __restrict__ uth, const ushort* __restrict__ utl,
    const ushort* __restrict__ W2s, const ushort* __restrict__ G2s,
    const ushort* __restrict__ Th2s, const ushort* __restrict__ Tl2s,
    const float2* __restrict__ P, float* __restrict__ yt) {
  int bid = blockIdx.x;
  int x = bid & 7;                     // XCD
  int d = x * 64 + ((bid >> 3) & 63);  // d-contiguous per XCD
  int b = bid >> 9;
  int tid = threadIdx.x;
  int l = tid & 63, wv = tid >> 6;
  int lr = l & 15, lk = l >> 4;
  int m0 = (wv & 1) * 16;              // c-half
  int half = wv >> 1;                  // n-half (B) / r-half (T,D)

  // Disjoint LDS map (total 43776 B):
  //  [0,4096)        u_hi  [32][128B]
  //  [4096,8192)     u_lo
  //  [8192,24832)    Sf    [32][130] f32
  //  [24832,33024)   Zs    [32][256B] S_excl bf16
  //  [33024,35072)   Tb    [4][64] float2
  //  [35072,43776)   ylds  [32][68] f32
  __shared__ __align__(16) char smem[43776];
  char*   u_hi = smem;
  char*   u_lo = smem + 4096;
  float*  Sf   = (float*)(smem + 8192);
  char*   Zs   = smem + 24832;
  float2* Tb   = (float2*)(smem + 33024);
  float*  ylds = (float*)(smem + 35072);

  // --- hoisted loads: W/Th/Tl fragments + P (in flight during stage)
  bf16x8 wf[8], tfh[4], tfl[4];
  {
    const ushort* Wd  = W2s  + (size_t)d * 8192 + (size_t)half * 4096;
    const ushort* Tdh = Th2s + (size_t)d * 4096 + (size_t)half * 2048;
    const ushort* Tdl = Tl2s + (size_t)d * 4096 + (size_t)half * 2048;
    #pragma unroll
    for (int t = 0; t < 4; ++t)
      #pragma unroll
      for (int ks = 0; ks < 2; ++ks)
        wf[t*2+ks] = *(const bf16x8*)(Wd + ((t*2 + ks)*64 + l)*8);
    #pragma unroll
    for (int t = 0; t < 2; ++t)
      #pragma unroll
      for (int ks = 0; ks < 2; ++ks) {
        tfh[t*2+ks] = *(const bf16x8*)(Tdh + ((t*2 + ks)*64 + l)*8);
        tfl[t*2+ks] = *(const bf16x8*)(Tdl + ((t*2 + ks)*64 + l)*8);
      }
  }
  float2 p0 = P[(size_t)d * NN + l];   // a^64 (lane l = state index n)

  // --- stage u_hi/u_lo (coalesced 16B loads), rows 0..31
  {
    size_t off = ((size_t)(b * DD + d)) * LL + tid * 8;
    uint4 vh = *(const uint4*)&uth[off];
    uint4 vl = *(const uint4*)&utl[off];
    int row = tid >> 3;
    int bo = row*128 + (((tid & 7) * 16) ^ ((row & 7) << 4));
    *(uint4*)(u_hi + bo) = vh;
    *(uint4*)(u_lo + bo) = vl;
  }
  __syncthreads();                     // [1]

  // --- B: Z-GEMM (u_hi) -> Sf rows c (de-interleaved re/im cols)
  {
    f32x4 acc[4] = {{0,0,0,0},{0,0,0,0},{0,0,0,0},{0,0,0,0}};
    #pragma unroll
    for (int ks = 0; ks < 2; ++ks) {
      int arow = m0 + lr;
      bf16x8 ah = *(const bf16x8*)(u_hi + arow*128 +
                     ((ks*64 + lk*16) ^ ((arow & 7) << 4)));
      #pragma unroll
      for (int t = 0; t < 4; ++t)
        acc[t] = __builtin_amdgcn_mfma_f32_16x16x32_bf16(ah, wf[t*2+ks], acc[t], 0,0,0);
    }
    #pragma unroll
    for (int t = 0; t < 4; ++t)
      #pragma unroll
      for (int j = 0; j < 4; ++j) {
        int c  = m0 + lk*4 + j;
        int n2 = half*64 + t*16 + lr;
        int col = (n2 >> 1) + (n2 & 1) * 64;
        Sf[c * 130 + col] = acc[t][j];
      }
  }

  // --- T: split-precision local conv GEMM into acc2
  f32x4 acc2[2] = {{0,0,0,0},{0,0,0,0}};
  {
    #pragma unroll
    for (int ks = 0; ks < 2; ++ks) {
      int arow = m0 + lr;
      int aoff = (ks*64 + lk*16) ^ ((arow & 7) << 4);
      bf16x8 ah = *(const bf16x8*)(u_hi + arow*128 + aoff);
      bf16x8 al = *(const bf16x8*)(u_lo + arow*128 + aoff);
      #pragma unroll
      for (int t = 0; t < 2; ++t) {
        acc2[t] = __builtin_amdgcn_mfma_f32_16x16x32_bf16(ah, tfh[t*2+ks], acc2[t], 0,0,0);
        acc2[t] = __builtin_amdgcn_mfma_f32_16x16x32_bf16(al, tfh[t*2+ks], acc2[t], 0,0,0);
        acc2[t] = __builtin_amdgcn_mfma_f32_16x16x32_bf16(ah, tfl[t*2+ks], acc2[t], 0,0,0);
      }
    }
  }

  // --- hoist G fragments (in flight across the scan)
  bf16x8 gf[8];
  {
    const ushort* Gd = G2s + (size_t)d * 8192 + (size_t)half * 4096;
    #pragma unroll
    for (int t = 0; t < 2; ++t)
      #pragma unroll
      for (int ks = 0; ks < 4; ++ks)
        gf[t*4+ks] = *(const bf16x8*)(Gd + ((t*4 + ks)*64 + l)*8);
  }
  __syncthreads();                     // [2] all Sf writes visible

  // --- register-chain scan: thread (l=n, wv) owns chunks c in [8wv, 8wv+8)
  {
    int n = l;
    float2 p = p0;
    float2 z[8], loc[8];
    #pragma unroll
    for (int j = 0; j < 8; ++j) {
      int r = wv*8 + j;
      z[j].x = Sf[r*130 + n];
      z[j].y = Sf[r*130 + 64 + n];
    }
    loc[0] = z[0];
    #pragma unroll
    for (int j = 1; j < 8; ++j)
      loc[j] = make_float2(fmaf(p.x, loc[j-1].x, fmaf(-p.y, loc[j-1].y, z[j].x)),
                           fmaf(p.x, loc[j-1].y, fmaf( p.y, loc[j-1].x, z[j].y)));
    Tb[wv*64 + n] = loc[7];
    float2 p2 = cmul(p, p), p4 = cmul(p2, p2), p8 = cmul(p4, p4);
    __syncthreads();                   // [3] Tb visible
    float2 Cw = make_float2(0.f, 0.f); // wave 0: stays 0 (S_excl[0]=0)
    for (int ww = 0; ww < wv; ++ww) {  // wave-uniform bound
      float2 t = Tb[ww*64 + n];
      Cw = make_float2(fmaf(p8.x, Cw.x, fmaf(-p8.y, Cw.y, t.x)),
                       fmaf(p8.x, Cw.y, fmaf( p8.y, Cw.x, t.y)));
    }
    // S_excl[8wv] = Cw; S_excl[8wv+j] = loc[j-1] + p^j*Cw
    float2 q = Cw;
    #pragma unroll
    for (int j = 0; j < 8; ++j) {
      float2 v;
      if (j == 0) v = q;
      else {
        q = cmul(p, q);
        v = make_float2(loc[j-1].x + q.x, loc[j-1].y + q.y);
      }
      int r = wv*8 + j;
      *(unsigned*)(Zs + r*256 + ((4*n) ^ ((r & 7) << 4))) =
          f2b(v.x) | (f2b(v.y) << 16);
    }
  }
  __syncthreads();                     // [4] Zs visible

  // --- D: cross GEMM accumulating into acc2
  {
    #pragma unroll
    for (int ks = 0; ks < 4; ++ks) {
      int arow = m0 + lr;
      bf16x8 ah = *(const bf16x8*)(Zs + arow*256 +
                     ((ks*64 + lk*16) ^ ((arow & 7) << 4)));
      #pragma unroll
      for (int t = 0; t < 2; ++t)
        acc2[t] = __builtin_amdgcn_mfma_f32_16x16x32_bf16(ah, gf[t*4+ks], acc2[t], 0,0,0);
    }
  }
  // --- out: acc2 -> ylds f32 [c][r] stride 68 (disjoint region) -> yt 8KB
  #pragma unroll
  for (int t = 0; t < 2; ++t)
    #pragma unroll
    for (int j = 0; j < 4; ++j) {
      int c = m0 + lk*4 + j;
      int r = half*32 + t*16 + lr;
      ylds[c*68 + r] = acc2[t][j];
    }
  __syncthreads();                     // [5] ylds visible
  {
    int row = tid >> 3, col = (tid & 7) * 8;
    float4 o0 = *(const float4*)&ylds[row*68 + col];
    float4 o1 = *(const float4*)&ylds[row*68 + col + 4];
    float* dst = &yt[((size_t)(b * DD + d)) * LL + tid * 8];
    *(float4*)dst = o0;
    *(float4*)(dst + 4) = o1;
  }
}

// ---------------------------------------------------------------------------
// K4: transpose yt[b][d][l] f32 -> y[b][l][d] f32. Full 64x64 coverage.
// ---------------------------------------------------------------------------
__global__ __launch_bounds__(256) void k4_tr(
    const float* __restrict__ yt, float* __restrict__ y) {
  int bid = blockIdx.x;
  int dt8 = bid & 7, lt = (bid >> 3) & 31, b = bid >> 8;
  int l0 = lt * 64, d0 = dt8 * 64;
  int tid = threadIdx.x;
  __shared__ float tl[64][65];         // [d][l]
  #pragma unroll
  for (int it = 0; it < 2; ++it) {
    int row = it * 32 + (tid >> 3), seg = tid & 7;   // row = d
    const float* src = &yt[((size_t)(b*DD + d0 + row))*LL + l0 + seg*8];
    float4 v0 = *(const float4*)src;
    float4 v1 = *(const float4*)(src + 4);
    tl[row][seg*8+0]=v0.x; tl[row][seg*8+1]=v0.y;
    tl[row][seg*8+2]=v0.z; tl[row][seg*8+3]=v0.w;
    tl[row][seg*8+4]=v1.x; tl[row][seg*8+5]=v1.y;
    tl[row][seg*8+6]=v1.z; tl[row][seg*8+7]=v1.w;
  }
  __syncthreads();
  #pragma unroll
  for (int it = 0; it < 2; ++it) {
    int row = it * 32 + (tid >> 3), seg = tid & 7;   // row = l
    float o[8];
    #pragma unroll
    for (int j = 0; j < 8; ++j) o[j] = tl[seg*8 + j][row];
    float* dst = &y[((size_t)(b*LL + l0 + row))*DD + d0 + seg*8];
    *(float4*)dst = *(float4*)&o[0];
    *(float4*)(dst + 4) = *(float4*)&o[4];
  }
}

extern "C" void kernel_launch(void* const* d_in, const int* in_sizes, int n_in,
                              void* d_out, int out_size, void* d_ws, size_t ws_size,
                              hipStream_t stream) {
  const float* u      = (const float*)d_in[0];
  const float* A_re   = (const float*)d_in[1];
  const float* A_im   = (const float*)d_in[2];
  const float* C_re   = (const float*)d_in[3];
  const float* C_im   = (const float*)d_in[4];
  const float* log_dt = (const float*)d_in[5];
  float* y = (float*)d_out;

  // ws: yt f32 33.5MB | uth 16.8 | utl 16.8 | W2s 8.4 | G2s 8.4 | Th 4.2 | Tl 4.2 | P
  float*  yt  = (float*)d_ws;
  ushort* uth = (ushort*)(yt + (size_t)BB * DD * LL);
  ushort* utl = uth + (size_t)BB * DD * LL;
  ushort* W2s = utl + (size_t)BB * DD * LL;
  ushort* G2s = W2s + (size_t)DD * 8192;
  ushort* Th  = G2s + (size_t)DD * 8192;
  ushort* Tl  = Th  + (size_t)DD * 4096;
  float2* P   = (float2*)(Tl + (size_t)DD * 4096);

  k0_tr   <<<BB * 32 * 8, 256, 0, stream>>>(u, uth, utl);
  k1_setup<<<DD,          256, 0, stream>>>(A_re, A_im, C_re, C_im, log_dt,
                                            W2s, G2s, Th, Tl, P);
  k2_mfma <<<BB * DD,     256, 0, stream>>>(uth, utl, W2s, G2s, Th, Tl, P, yt);
  k4_tr   <<<BB * 32 * 8, 256, 0, stream>>>(yt, y);
}

// Round 15
// 62.675 us; speedup vs baseline: 1.1634x; 1.0106x over previous
//
#include <hip/hip_runtime.h>

#define BB 8
#define LL 2048
#define DD 512
#define NN 64
#define TT 64
#define CC 32   // LL/TT chunks

typedef __attribute__((ext_vector_type(8))) short bf16x8;
typedef __attribute__((ext_vector_type(4))) float f32x4;

__device__ __forceinline__ float2 cmul(float2 a, float2 b) {
  return make_float2(a.x*b.x - a.y*b.y, a.x*b.y + a.y*b.x);
}
__device__ __forceinline__ unsigned f2b(float f) {   // f32 -> bf16 (RNE)
  union { float f; unsigned u; } v; v.f = f;
  return (v.u + 0x7FFFu + ((v.u >> 16) & 1u)) >> 16;
}
__device__ __forceinline__ float b2f(unsigned h) {
  union { unsigned u; float f; } v; v.u = h << 16; return v.f;
}

// ---------------------------------------------------------------------------
// K0: transpose u[b][l][d] f32 -> ut_hi/ut_lo[b][d][l] bf16 (hi + residual).
// ---------------------------------------------------------------------------
__global__ __launch_bounds__(256) void k0_tr(
    const float* __restrict__ u, ushort* __restrict__ uth,
    ushort* __restrict__ utl) {
  int bid = blockIdx.x;
  int dt8 = bid & 7, lt = (bid >> 3) & 31, b = bid >> 8;
  int l0 = lt * 64, d0 = dt8 * 64;
  int tid = threadIdx.x;
  __shared__ float tl[64][65];         // [l][d]
  #pragma unroll
  for (int it = 0; it < 2; ++it) {
    int row = it * 32 + (tid >> 3), seg = tid & 7;   // row = l
    const float* src = &u[((size_t)(b*LL + l0 + row))*DD + d0 + seg*8];
    float4 v0 = *(const float4*)src;
    float4 v1 = *(const float4*)(src + 4);
    tl[row][seg*8+0]=v0.x; tl[row][seg*8+1]=v0.y;
    tl[row][seg*8+2]=v0.z; tl[row][seg*8+3]=v0.w;
    tl[row][seg*8+4]=v1.x; tl[row][seg*8+5]=v1.y;
    tl[row][seg*8+6]=v1.z; tl[row][seg*8+7]=v1.w;
  }
  __syncthreads();
  #pragma unroll
  for (int it = 0; it < 2; ++it) {
    int row = it * 32 + (tid >> 3), seg = tid & 7;   // row = d
    unsigned h[8], lo[8];
    #pragma unroll
    for (int j = 0; j < 8; ++j) {
      float f = tl[seg*8 + j][row];
      h[j]  = f2b(f);
      lo[j] = f2b(f - b2f(h[j]));
    }
    uint4 ph = make_uint4(h[0]|(h[1]<<16), h[2]|(h[3]<<16),
                          h[4]|(h[5]<<16), h[6]|(h[7]<<16));
    uint4 pl = make_uint4(lo[0]|(lo[1]<<16), lo[2]|(lo[3]<<16),
                          lo[4]|(lo[5]<<16), lo[6]|(lo[7]<<16));
    size_t off = ((size_t)(b*DD + d0 + row))*LL + l0 + seg*8;
    *(uint4*)&uth[off] = ph;
    *(uint4*)&utl[off] = pl;
  }
}

// ---------------------------------------------------------------------------
// K1: per-d setup, 256 threads (wave wv owns a 16-slice of s/r/m).
// Emits pre-swizzled bf16 MFMA B-operand tables W2s/G2s/Th/Tl + P (f32).
// ---------------------------------------------------------------------------
__global__ __launch_bounds__(256) void k1_setup(
    const float* __restrict__ A_re, const float* __restrict__ A_im,
    const float* __restrict__ C_re, const float* __restrict__ C_im,
    const float* __restrict__ log_dt,
    ushort* __restrict__ W2s, ushort* __restrict__ G2s,
    ushort* __restrict__ Th2s, ushort* __restrict__ Tl2s,
    float2* __restrict__ P) {
  int d = blockIdx.x;
  int tid = threadIdx.x;
  int n = tid & 63, wv = tid >> 6;
  int idx = d * NN + n;

  __shared__ ushort Wl[8192], Gl[8192];
  __shared__ __align__(16) char smU[16640];   // Kp f32[64][65] | later Th/Tl
  ushort* Thl = (ushort*)smU;
  ushort* Tll = (ushort*)(smU + 8192);
  float*  Kp  = (float*)smU;
  __shared__ float Kq[64][5];
  __shared__ float Kl[64];

  float dt  = expf(log_dt[d]);
  float dre = dt * A_re[idx], dim = dt * A_im[idx];
  float er  = expf(dre);
  float abr = er * cosf(dim), abi = er * sinf(dim);
  const float eps = 1e-8f;
  float nre = abr - 1.0f + eps, nim = abi;
  float qre = dre + eps,        qim = dim;
  float inv = 1.0f / (qre*qre + qim*qim);
  float bbr = dt * (nre*qre + nim*qim) * inv;
  float bbi = dt * (nim*qre - nre*qim) * inv;
  float2 a  = make_float2(abr, abi);
  float2 bb = make_float2(bbr, bbi);
  float2 cc = make_float2(C_re[idx], C_im[idx]);

  float2 a2  = cmul(a, a),   a4  = cmul(a2, a2);
  float2 a8  = cmul(a4, a4), a16 = cmul(a8, a8);
  float2 a32 = cmul(a16, a16), a48 = cmul(a32, a16);
  float2 pw_wv = make_float2(1.f, 0.f);
  for (int q = 0; q < wv; ++q) pw_wv = cmul(pw_wv, a16);

  if (wv == 0) P[idx] = cmul(a32, a32);

  // W slice: s in [wv*16, wv*16+15], descending; W[s] = bb*a^(63-s)
  {
    float2 sel = (wv == 0) ? a48 : (wv == 1) ? a32
               : (wv == 2) ? a16 : make_float2(1.f, 0.f);
    float2 w = cmul(bb, sel);
    for (int j = 15; j >= 0; --j) {
      int s = wv*16 + j;
      int ks = s >> 5, lk = (s >> 3) & 3, e = s & 7;
      {
        int n2 = 2*n; int nh = n2>>6, tq = (n2>>4)&3, lr = n2&15;
        Wl[(((nh*4+tq)*2+ks)*64 + lk*16+lr)*8 + e] = (ushort)f2b(w.x);
      }
      {
        int n2 = 2*n+1; int nh = n2>>6, tq = (n2>>4)&3, lr = n2&15;
        Wl[(((nh*4+tq)*2+ks)*64 + lk*16+lr)*8 + e] = (ushort)f2b(w.y);
      }
      w = cmul(w, a);
    }
  }
  // G slice: r in [wv*16, wv*16+15]; G[r] = cc*a^(r+1)
  {
    float2 g = cmul(cc, cmul(a, pw_wv));
    for (int j = 0; j < 16; ++j) {
      int r = wv*16 + j;
      int rh = r >> 5, tq = (r >> 4) & 1, lr = r & 15;
      {
        int n2 = 2*n; int ks = n2>>5, lk = (n2>>3)&3, e = n2&7;
        Gl[(((rh*2+tq)*4+ks)*64 + lk*16+lr)*8 + e] = (ushort)f2b(g.x);
      }
      {
        int n2 = 2*n+1; int ks = n2>>5, lk = (n2>>3)&3, e = n2&7;
        Gl[(((rh*2+tq)*4+ks)*64 + lk*16+lr)*8 + e] = (ushort)f2b(-g.y);
      }
      g = cmul(g, a);
    }
  }
  // K slice: Kp[m][n] = Re(cb * a^m), m in [wv*16, wv*16+15]
  {
    float2 cb = cmul(cc, bb);
    float2 t = cmul(cb, pw_wv);
    for (int j = 0; j < 16; ++j) {
      Kp[(wv*16 + j)*65 + n] = t.x;
      t = cmul(t, a);
    }
  }
  __syncthreads();
  {
    int m = tid >> 2, q = tid & 3;
    float s = 0.f;
    #pragma unroll
    for (int j = 0; j < 16; ++j) s += Kp[m*65 + q*16 + j];
    Kq[m][q] = s;
  }
  __syncthreads();
  if (tid < 64) Kl[tid] = Kq[tid][0] + Kq[tid][1] + Kq[tid][2] + Kq[tid][3];
  __syncthreads();                     // Kl ready; Kp dead -> Th/Tl reuse smU

  // Toeplitz frags (hi+lo): wave wv = (t*2+ks); 16 elems/thread
  {
    int tq = wv >> 1, ks = wv & 1;
    #pragma unroll
    for (int rh = 0; rh < 2; ++rh) {
      int r = rh*32 + tq*16 + (n & 15);
      #pragma unroll
      for (int e = 0; e < 8; ++e) {
        int s = ks*32 + (n >> 4)*8 + e;
        float val = (s <= r) ? Kl[r - s] : 0.f;
        unsigned hv = f2b(val);
        int o = rh*2048 + (wv*64 + n)*8 + e;
        Thl[o] = (ushort)hv;
        Tll[o] = (ushort)f2b(val - b2f(hv));
      }
    }
  }
  __syncthreads();
  {
    uint4* Wg  = (uint4*)(W2s  + (size_t)d * 8192);
    uint4* Gg  = (uint4*)(G2s  + (size_t)d * 8192);
    uint4* Thg = (uint4*)(Th2s + (size_t)d * 4096);
    uint4* Tlg = (uint4*)(Tl2s + (size_t)d * 4096);
    #pragma unroll
    for (int i = tid; i < 1024; i += 256) {
      Wg[i] = ((const uint4*)Wl)[i];
      Gg[i] = ((const uint4*)Gl)[i];
    }
    #pragma unroll
    for (int i = tid; i < 512; i += 256) {
      Thg[i] = ((const uint4*)Thl)[i];
      Tlg[i] = ((const uint4*)Tll)[i];
    }
  }
}

// ---------------------------------------------------------------------------
// K2 MFMA: Z-GEMM (u hi+lo) + split Toeplitz conv + register-chain scan +
// cross-GEMM; phase-D accumulators stored DIRECTLY to yt (no ylds staging).
// FULLY DISJOINT LDS (35.1KB -> 4 blocks/CU); 4 barriers.
// Scan: thread (n,wv) owns chunks [8wv,8wv+8): 7 in-register cmuls, one Tb
// write, 1 barrier, <=3-term cross-wave combine with p^8 (wave-uniform).
// ---------------------------------------------------------------------------
__global__ __launch_bounds__(256, 4) void k2_mfma(
    const ushort* __restrict__ uth, const ushort* __restrict__ utl,
    const ushort* __restrict__ W2s, const ushort* __restrict__ G2s,
    const ushort* __restrict__ Th2s, const ushort* __restrict__ Tl2s,
    const float2* __restrict__ P, float* __restrict__ yt) {
  int bid = blockIdx.x;
  int x = bid & 7;                     // XCD
  int d = x * 64 + ((bid >> 3) & 63);  // d-contiguous per XCD
  int b = bid >> 9;
  int tid = threadIdx.x;
  int l = tid & 63, wv = tid >> 6;
  int lr = l & 15, lk = l >> 4;
  int m0 = (wv & 1) * 16;              // c-half
  int half = wv >> 1;                  // n-half (B) / r-half (T,D)

  // Disjoint LDS map (total 35072 B -> 4 blocks/CU):
  //  [0,4096)        u_hi  [32][128B]
  //  [4096,8192)     u_lo
  //  [8192,24832)    Sf    [32][130] f32
  //  [24832,33024)   Zs    [32][256B] S_excl bf16
  //  [33024,35072)   Tb    [4][64] float2
  __shared__ __align__(16) char smem[35072];
  char*   u_hi = smem;
  char*   u_lo = smem + 4096;
  float*  Sf   = (float*)(smem + 8192);
  char*   Zs   = smem + 24832;
  float2* Tb   = (float2*)(smem + 33024);

  // --- hoisted loads: W/Th/Tl fragments + P (in flight during stage)
  bf16x8 wf[8], tfh[4], tfl[4];
  {
    const ushort* Wd  = W2s  + (size_t)d * 8192 + (size_t)half * 4096;
    const ushort* Tdh = Th2s + (size_t)d * 4096 + (size_t)half * 2048;
    const ushort* Tdl = Tl2s + (size_t)d * 4096 + (size_t)half * 2048;
    #pragma unroll
    for (int t = 0; t < 4; ++t)
      #pragma unroll
      for (int ks = 0; ks < 2; ++ks)
        wf[t*2+ks] = *(const bf16x8*)(Wd + ((t*2 + ks)*64 + l)*8);
    #pragma unroll
    for (int t = 0; t < 2; ++t)
      #pragma unroll
      for (int ks = 0; ks < 2; ++ks) {
        tfh[t*2+ks] = *(const bf16x8*)(Tdh + ((t*2 + ks)*64 + l)*8);
        tfl[t*2+ks] = *(const bf16x8*)(Tdl + ((t*2 + ks)*64 + l)*8);
      }
  }
  float2 p0 = P[(size_t)d * NN + l];   // a^64 (lane l = state index n)

  // --- stage u_hi/u_lo (coalesced 16B loads), rows 0..31
  {
    size_t off = ((size_t)(b * DD + d)) * LL + tid * 8;
    uint4 vh = *(const uint4*)&uth[off];
    uint4 vl = *(const uint4*)&utl[off];
    int row = tid >> 3;
    int bo = row*128 + (((tid & 7) * 16) ^ ((row & 7) << 4));
    *(uint4*)(u_hi + bo) = vh;
    *(uint4*)(u_lo + bo) = vl;
  }
  __syncthreads();                     // [1]

  // --- B: Z-GEMM (u hi+lo) -> Sf rows c (de-interleaved re/im cols)
  {
    f32x4 acc[4] = {{0,0,0,0},{0,0,0,0},{0,0,0,0},{0,0,0,0}};
    #pragma unroll
    for (int ks = 0; ks < 2; ++ks) {
      int arow = m0 + lr;
      int aoff = (ks*64 + lk*16) ^ ((arow & 7) << 4);
      bf16x8 ah = *(const bf16x8*)(u_hi + arow*128 + aoff);
      bf16x8 al = *(const bf16x8*)(u_lo + arow*128 + aoff);
      #pragma unroll
      for (int t = 0; t < 4; ++t) {
        acc[t] = __builtin_amdgcn_mfma_f32_16x16x32_bf16(ah, wf[t*2+ks], acc[t], 0,0,0);
        acc[t] = __builtin_amdgcn_mfma_f32_16x16x32_bf16(al, wf[t*2+ks], acc[t], 0,0,0);
      }
    }
    #pragma unroll
    for (int t = 0; t < 4; ++t)
      #pragma unroll
      for (int j = 0; j < 4; ++j) {
        int c  = m0 + lk*4 + j;
        int n2 = half*64 + t*16 + lr;
        int col = (n2 >> 1) + (n2 & 1) * 64;
        Sf[c * 130 + col] = acc[t][j];
      }
  }

  // --- T: split-precision local conv GEMM into acc2
  f32x4 acc2[2] = {{0,0,0,0},{0,0,0,0}};
  {
    #pragma unroll
    for (int ks = 0; ks < 2; ++ks) {
      int arow = m0 + lr;
      int aoff = (ks*64 + lk*16) ^ ((arow & 7) << 4);
      bf16x8 ah = *(const bf16x8*)(u_hi + arow*128 + aoff);
      bf16x8 al = *(const bf16x8*)(u_lo + arow*128 + aoff);
      #pragma unroll
      for (int t = 0; t < 2; ++t) {
        acc2[t] = __builtin_amdgcn_mfma_f32_16x16x32_bf16(ah, tfh[t*2+ks], acc2[t], 0,0,0);
        acc2[t] = __builtin_amdgcn_mfma_f32_16x16x32_bf16(al, tfh[t*2+ks], acc2[t], 0,0,0);
        acc2[t] = __builtin_amdgcn_mfma_f32_16x16x32_bf16(ah, tfl[t*2+ks], acc2[t], 0,0,0);
      }
    }
  }

  // --- hoist G fragments (in flight across the scan)
  bf16x8 gf[8];
  {
    const ushort* Gd = G2s + (size_t)d * 8192 + (size_t)half * 4096;
    #pragma unroll
    for (int t = 0; t < 2; ++t)
      #pragma unroll
      for (int ks = 0; ks < 4; ++ks)
        gf[t*4+ks] = *(const bf16x8*)(Gd + ((t*4 + ks)*64 + l)*8);
  }
  __syncthreads();                     // [2] all Sf writes visible

  // --- register-chain scan: thread (l=n, wv) owns chunks c in [8wv, 8wv+8)
  {
    int n = l;
    float2 p = p0;
    float2 z[8], loc[8];
    #pragma unroll
    for (int j = 0; j < 8; ++j) {
      int r = wv*8 + j;
      z[j].x = Sf[r*130 + n];
      z[j].y = Sf[r*130 + 64 + n];
    }
    loc[0] = z[0];
    #pragma unroll
    for (int j = 1; j < 8; ++j)
      loc[j] = make_float2(fmaf(p.x, loc[j-1].x, fmaf(-p.y, loc[j-1].y, z[j].x)),
                           fmaf(p.x, loc[j-1].y, fmaf( p.y, loc[j-1].x, z[j].y)));
    Tb[wv*64 + n] = loc[7];
    float2 p2 = cmul(p, p), p4 = cmul(p2, p2), p8 = cmul(p4, p4);
    __syncthreads();                   // [3] Tb visible
    float2 Cw = make_float2(0.f, 0.f); // wave 0: stays 0 (S_excl[0]=0)
    for (int ww = 0; ww < wv; ++ww) {  // wave-uniform bound
      float2 t = Tb[ww*64 + n];
      Cw = make_float2(fmaf(p8.x, Cw.x, fmaf(-p8.y, Cw.y, t.x)),
                       fmaf(p8.x, Cw.y, fmaf( p8.y, Cw.x, t.y)));
    }
    // S_excl[8wv] = Cw; S_excl[8wv+j] = loc[j-1] + p^j*Cw
    float2 q = Cw;
    #pragma unroll
    for (int j = 0; j < 8; ++j) {
      float2 v;
      if (j == 0) v = q;
      else {
        q = cmul(p, q);
        v = make_float2(loc[j-1].x + q.x, loc[j-1].y + q.y);
      }
      int r = wv*8 + j;
      *(unsigned*)(Zs + r*256 + ((4*n) ^ ((r & 7) << 4))) =
          f2b(v.x) | (f2b(v.y) << 16);
    }
  }
  __syncthreads();                     // [4] Zs visible

  // --- D: cross GEMM accumulating into acc2
  {
    #pragma unroll
    for (int ks = 0; ks < 4; ++ks) {
      int arow = m0 + lr;
      bf16x8 ah = *(const bf16x8*)(Zs + arow*256 +
                     ((ks*64 + lk*16) ^ ((arow & 7) << 4)));
      #pragma unroll
      for (int t = 0; t < 2; ++t)
        acc2[t] = __builtin_amdgcn_mfma_f32_16x16x32_bf16(ah, gf[t*4+ks], acc2[t], 0,0,0);
    }
  }
  // --- out: direct global stores (64B contiguous per 16 lanes)
  {
    float* dst = &yt[((size_t)(b * DD + d)) * LL];
    #pragma unroll
    for (int t = 0; t < 2; ++t)
      #pragma unroll
      for (int j = 0; j < 4; ++j) {
        int c = m0 + lk*4 + j;
        int r = half*32 + t*16 + lr;
        dst[c*64 + r] = acc2[t][j];
      }
  }
}

// ---------------------------------------------------------------------------
// K4: transpose yt[b][d][l] f32 -> y[b][l][d] f32. Full 64x64 coverage.
// ---------------------------------------------------------------------------
__global__ __launch_bounds__(256) void k4_tr(
    const float* __restrict__ yt, float* __restrict__ y) {
  int bid = blockIdx.x;
  int dt8 = bid & 7, lt = (bid >> 3) & 31, b = bid >> 8;
  int l0 = lt * 64, d0 = dt8 * 64;
  int tid = threadIdx.x;
  __shared__ float tl[64][65];         // [d][l]
  #pragma unroll
  for (int it = 0; it < 2; ++it) {
    int row = it * 32 + (tid >> 3), seg = tid & 7;   // row = d
    const float* src = &yt[((size_t)(b*DD + d0 + row))*LL + l0 + seg*8];
    float4 v0 = *(const float4*)src;
    float4 v1 = *(const float4*)(src + 4);
    tl[row][seg*8+0]=v0.x; tl[row][seg*8+1]=v0.y;
    tl[row][seg*8+2]=v0.z; tl[row][seg*8+3]=v0.w;
    tl[row][seg*8+4]=v1.x; tl[row][seg*8+5]=v1.y;
    tl[row][seg*8+6]=v1.z; tl[row][seg*8+7]=v1.w;
  }
  __syncthreads();
  #pragma unroll
  for (int it = 0; it < 2; ++it) {
    int row = it * 32 + (tid >> 3), seg = tid & 7;   // row = l
    float o[8];
    #pragma unroll
    for (int j = 0; j < 8; ++j) o[j] = tl[seg*8 + j][row];
    float* dst = &y[((size_t)(b*LL + l0 + row))*DD + d0 + seg*8];
    *(float4*)dst = *(float4*)&o[0];
    *(float4*)(dst + 4) = *(float4*)&o[4];
  }
}

extern "C" void kernel_launch(void* const* d_in, const int* in_sizes, int n_in,
                              void* d_out, int out_size, void* d_ws, size_t ws_size,
                              hipStream_t stream) {
  const float* u      = (const float*)d_in[0];
  const float* A_re   = (const float*)d_in[1];
  const float* A_im   = (const float*)d_in[2];
  const float* C_re   = (const float*)d_in[3];
  const float* C_im   = (const float*)d_in[4];
  const float* log_dt = (const float*)d_in[5];
  float* y = (float*)d_out;

  // ws: yt f32 33.5MB | uth 16.8 | utl 16.8 | W2s 8.4 | G2s 8.4 | Th 4.2 | Tl 4.2 | P
  float*  yt  = (float*)d_ws;
  ushort* uth = (ushort*)(yt + (size_t)BB * DD * LL);
  ushort* utl = uth + (size_t)BB * DD * LL;
  ushort* W2s = utl + (size_t)BB * DD * LL;
  ushort* G2s = W2s + (size_t)DD * 8192;
  ushort* Th  = G2s + (size_t)DD * 8192;
  ushort* Tl  = Th  + (size_t)DD * 4096;
  float2* P   = (float2*)(Tl + (size_t)DD * 4096);

  k0_tr   <<<BB * 32 * 8, 256, 0, stream>>>(u, uth, utl);
  k1_setup<<<DD,          256, 0, stream>>>(A_re, A_im, C_re, C_im, log_dt,
                                            W2s, G2s, Th, Tl, P);
  k2_mfma <<<BB * DD,     256, 0, stream>>>(uth, utl, W2s, G2s, Th, Tl, P, yt);
  k4_tr   <<<BB * 32 * 8, 256, 0, stream>>>(yt, y);
}